// Round 13
// baseline (765.865 us; speedup 1.0000x reference)
//
#include <hip/hip_runtime.h>
#include <math.h>

#define HWN 65536

typedef __attribute__((ext_vector_type(8))) short bf16x8;
typedef __attribute__((ext_vector_type(4))) float f32x4;

__device__ __forceinline__ float sgm(float x){ return 1.0f/(1.0f+expf(-x)); }

__device__ __forceinline__ unsigned pack_hi2(float a, float b){
    // [b_hi16 : a_hi16] -- two truncated bf16s, low half = a
    return (__float_as_uint(b) & 0xFFFF0000u) | (__float_as_uint(a) >> 16);
}

__device__ __forceinline__ void fma4(float acc[4], const float4 w,
                                     const float4 x0, const float4 x1,
                                     const float4 x2, const float4 x3){
    acc[0] += w.x*x0.x + w.y*x1.x + w.z*x2.x + w.w*x3.x;
    acc[1] += w.x*x0.y + w.y*x1.y + w.z*x2.y + w.w*x3.y;
    acc[2] += w.x*x0.z + w.y*x1.z + w.z*x2.z + w.w*x3.z;
    acc[3] += w.x*x0.w + w.y*x1.w + w.z*x2.w + w.w*x3.w;
}

// ---------------------------------------------------------------------------
// K1: input_proj + lb store + lgce_pre (+pooled partials) + qkv + gate.
// R9 fp32 structure (8 px/thread, 128 px/block, unroll 2): 310 us, VGPR 128.
// Split-bf16 MFMA on k1 FALSIFIED (R11, 1.56e-2): q/k errors flip rank-topk;
// gate feeds floor() cliff. k1 stays fp32.
// launch_bounds(256,2): NEVER raise arg2 (R3: VGPR 64 -> 4 GB spill).
// ---------------------------------------------------------------------------
__global__ __launch_bounds__(256,2) void k1_proj(
    const float* __restrict__ x,   const float* __restrict__ Wp,
    const float* __restrict__ Wpre,const float* __restrict__ bpre,
    const float* __restrict__ Wqkv,
    const float* __restrict__ Wg1, const float* __restrict__ bg1,
    const float* __restrict__ wg2, const float* __restrict__ bg2,
    float* __restrict__ lb, float* __restrict__ pre, float* __restrict__ qkv,
    float* __restrict__ pooled_part, float* __restrict__ gate_part)
{
    __shared__ float st[128*128];         // 64 KB: x staging -> proj output -> ht alias
    float4* st4 = (float4*)st;
    float*  ht  = st;                     // 32x128 floats = 16 KB, used after barrier

    const int t    = threadIdx.x;
    const int blk  = blockIdx.x;
    const int b    = blk >> 9;            // 512 blocks per batch
    const int p0   = (blk & 511) << 7;    // 128 px / block
    const int pg   = t & 15;              // pixel group: px pg*4..+3 and 64+pg*4..+3
    const int og   = t >> 4;              // output group
    const int slot = blk & 63;

    const float4* x4 = (const float4*)x;

    // ---- stage all of x (one burst)
    #pragma unroll
    for (int i = 0; i < 16; ++i) {
        int idx = t + 256*i;
        int c = idx >> 5, q = idx & 31;
        st4[c*32 + q] = x4[(size_t)(b*128 + c)*16384 + (p0>>2) + q];
    }
    __syncthreads();

    // ---- proj (128x128): og owns outs og*8..+7, 8 px each -> acc[8][8]
    {
        const int o0 = og*8;
        float acc[8][8];
        #pragma unroll
        for (int j=0;j<8;++j)
            #pragma unroll
            for (int k=0;k<8;++k) acc[j][k]=0.f;
        const float4* W4 = (const float4*)Wp;
        #pragma unroll 2
        for (int c = 0; c < 128; c += 4) {
            float4 xa0 = st4[(c+0)*32 + pg],      xb0 = st4[(c+0)*32 + 16 + pg];
            float4 xa1 = st4[(c+1)*32 + pg],      xb1 = st4[(c+1)*32 + 16 + pg];
            float4 xa2 = st4[(c+2)*32 + pg],      xb2 = st4[(c+2)*32 + 16 + pg];
            float4 xa3 = st4[(c+3)*32 + pg],      xb3 = st4[(c+3)*32 + 16 + pg];
            #pragma unroll
            for (int j = 0; j < 8; ++j) {
                float4 w = W4[(o0+j)*32 + (c>>2)];
                fma4(&acc[j][0], w, xa0,xa1,xa2,xa3);
                fma4(&acc[j][4], w, xb0,xb1,xb2,xb3);
            }
        }
        __syncthreads();   // every thread done READING x before any overwrite

        #pragma unroll
        for (int j = 0; j < 8; ++j) {
            st4[(o0+j)*32 + pg]      = make_float4(acc[j][0],acc[j][1],acc[j][2],acc[j][3]);
            st4[(o0+j)*32 + 16 + pg] = make_float4(acc[j][4],acc[j][5],acc[j][6],acc[j][7]);
        }
        if (og < 8) {      // lb = proj channels 0..63, straight from registers
            float4* lb4 = (float4*)lb;
            #pragma unroll
            for (int j = 0; j < 8; ++j) {
                lb4[(size_t)(b*64 + o0+j)*16384 + (p0>>2) + pg] =
                    make_float4(acc[j][0],acc[j][1],acc[j][2],acc[j][3]);
                lb4[(size_t)(b*64 + o0+j)*16384 + (p0>>2) + 16 + pg] =
                    make_float4(acc[j][4],acc[j][5],acc[j][6],acc[j][7]);
            }
        }
    }
    __syncthreads();       // proj output ready

    // ---- pre conv (64x64): og owns 4 outs -> acc[4][8]; + pooled partials
    {
        const int o0 = og*4;
        float acc[4][8];
        #pragma unroll
        for (int j=0;j<4;++j)
            #pragma unroll
            for (int k=0;k<8;++k) acc[j][k]=0.f;
        const float4* W4 = (const float4*)Wpre;
        #pragma unroll 2
        for (int c = 0; c < 64; c += 4) {
            float4 xa0 = st4[(c+0)*32 + pg],      xb0 = st4[(c+0)*32 + 16 + pg];
            float4 xa1 = st4[(c+1)*32 + pg],      xb1 = st4[(c+1)*32 + 16 + pg];
            float4 xa2 = st4[(c+2)*32 + pg],      xb2 = st4[(c+2)*32 + 16 + pg];
            float4 xa3 = st4[(c+3)*32 + pg],      xb3 = st4[(c+3)*32 + 16 + pg];
            #pragma unroll
            for (int j = 0; j < 4; ++j) {
                float4 w = W4[(o0+j)*16 + (c>>2)];
                fma4(&acc[j][0], w, xa0,xa1,xa2,xa3);
                fma4(&acc[j][4], w, xb0,xb1,xb2,xb3);
            }
        }
        float4* pre4 = (float4*)pre;
        #pragma unroll
        for (int j = 0; j < 4; ++j) {
            float bs = bpre[o0+j];
            float4 v0 = make_float4(acc[j][0]+bs, acc[j][1]+bs, acc[j][2]+bs, acc[j][3]+bs);
            float4 v1 = make_float4(acc[j][4]+bs, acc[j][5]+bs, acc[j][6]+bs, acc[j][7]+bs);
            pre4[(size_t)(b*64 + o0+j)*16384 + (p0>>2) + pg]      = v0;
            pre4[(size_t)(b*64 + o0+j)*16384 + (p0>>2) + 16 + pg] = v1;
            float s = v0.x+v0.y+v0.z+v0.w + v1.x+v1.y+v1.z+v1.w;
            s += __shfl_xor(s,1); s += __shfl_xor(s,2);
            s += __shfl_xor(s,4); s += __shfl_xor(s,8);
            if (pg == 0) atomicAdd(&pooled_part[slot*256 + b*64 + o0 + j], s);
        }
    }

    // ---- qkv conv (192x64): og owns 12 outs, 2 chunks of 6 -> acc[6][8]
    #pragma unroll
    for (int chk = 0; chk < 2; ++chk) {
        const int o0 = og*12 + chk*6;
        float acc[6][8];
        #pragma unroll
        for (int j=0;j<6;++j)
            #pragma unroll
            for (int k=0;k<8;++k) acc[j][k]=0.f;
        const float4* W4 = (const float4*)Wqkv;
        #pragma unroll 2
        for (int c = 0; c < 64; c += 4) {
            float4 xa0 = st4[(64+c+0)*32 + pg],   xb0 = st4[(64+c+0)*32 + 16 + pg];
            float4 xa1 = st4[(64+c+1)*32 + pg],   xb1 = st4[(64+c+1)*32 + 16 + pg];
            float4 xa2 = st4[(64+c+2)*32 + pg],   xb2 = st4[(64+c+2)*32 + 16 + pg];
            float4 xa3 = st4[(64+c+3)*32 + pg],   xb3 = st4[(64+c+3)*32 + 16 + pg];
            #pragma unroll
            for (int j = 0; j < 6; ++j) {
                float4 w = W4[(o0+j)*16 + (c>>2)];
                fma4(&acc[j][0], w, xa0,xa1,xa2,xa3);
                fma4(&acc[j][4], w, xb0,xb1,xb2,xb3);
            }
        }
        float4* qkv4 = (float4*)qkv;
        #pragma unroll
        for (int j = 0; j < 6; ++j) {
            qkv4[(size_t)(b*192 + o0+j)*16384 + (p0>>2) + pg] =
                make_float4(acc[j][0],acc[j][1],acc[j][2],acc[j][3]);
            qkv4[(size_t)(b*192 + o0+j)*16384 + (p0>>2) + 16 + pg] =
                make_float4(acc[j][4],acc[j][5],acc[j][6],acc[j][7]);
        }
    }

    // ---- gate hidden (32x64): og owns 2 outs -> acc[2][8], held across barrier
    {
        const int o0 = og*2;
        float acc[2][8];
        #pragma unroll
        for (int j=0;j<2;++j)
            #pragma unroll
            for (int k=0;k<8;++k) acc[j][k]=0.f;
        const float4* W4 = (const float4*)Wg1;
        for (int c = 0; c < 64; c += 4) {
            float4 xa0 = st4[(64+c+0)*32 + pg],   xb0 = st4[(64+c+0)*32 + 16 + pg];
            float4 xa1 = st4[(64+c+1)*32 + pg],   xb1 = st4[(64+c+1)*32 + 16 + pg];
            float4 xa2 = st4[(64+c+2)*32 + pg],   xb2 = st4[(64+c+2)*32 + 16 + pg];
            float4 xa3 = st4[(64+c+3)*32 + pg],   xb3 = st4[(64+c+3)*32 + 16 + pg];
            #pragma unroll
            for (int j = 0; j < 2; ++j) {
                float4 w = W4[(o0+j)*16 + (c>>2)];
                fma4(&acc[j][0], w, xa0,xa1,xa2,xa3);
                fma4(&acc[j][4], w, xb0,xb1,xb2,xb3);
            }
        }
        __syncthreads();   // ALL pt reads complete before ht overwrites st
        #pragma unroll
        for (int j = 0; j < 2; ++j) {
            float bs = bg1[o0+j];
            #pragma unroll
            for (int k = 0; k < 4; ++k) {
                ht[(o0+j)*128 + pg*4 + k]      = fmaxf(acc[j][k]+bs,   0.0f);
                ht[(o0+j)*128 + 64 + pg*4 + k] = fmaxf(acc[j][4+k]+bs, 0.0f);
            }
        }
    }
    __syncthreads();

    // ---- gate scalar: 128 px, 2 waves, wave-reduce + atomic each
    if (t < 128) {
        float g = bg2[0];
        #pragma unroll
        for (int c = 0; c < 32; ++c) g += wg2[c]*ht[c*128 + t];
        g = sgm(g);
        g += __shfl_xor(g,1);  g += __shfl_xor(g,2);  g += __shfl_xor(g,4);
        g += __shfl_xor(g,8);  g += __shfl_xor(g,16); g += __shfl_xor(g,32);
        if ((t & 63) == 0) atomicAdd(&gate_part[slot], g);
    }
}

// ---------------------------------------------------------------------------
// K2: pooled -> cw, gate mean -> kdyn. single block.
// ---------------------------------------------------------------------------
__global__ void k2_small(const float* __restrict__ pooled_part,
                         const float* __restrict__ gate_part,
                         const float* __restrict__ w1, const float* __restrict__ b1,
                         const float* __restrict__ w2, const float* __restrict__ b2,
                         float* __restrict__ cw, float* __restrict__ kdyn)
{
    __shared__ float pl[256];
    const int t = threadIdx.x;
    float s = 0.f;
    for (int sl = 0; sl < 64; ++sl) s += pooled_part[sl*256 + t];
    pl[t] = s * (1.0f/65536.0f);
    __syncthreads();
    const int b = t >> 6, g = (t >> 3) & 7, c = t & 7;
    float h0 = b1[g*2+0], h1 = b1[g*2+1];
    #pragma unroll
    for (int cc = 0; cc < 8; ++cc) {
        float p = pl[b*64 + g*8 + cc];
        h0 += p*w1[g*16 + 0*8 + cc];
        h1 += p*w1[g*16 + 1*8 + cc];
    }
    h0 = fmaxf(h0, 0.f); h1 = fmaxf(h1, 0.f);
    cw[t] = sgm(h0*w2[g*16 + c*2 + 0] + h1*w2[g*16 + c*2 + 1] + b2[g*8+c]);
    if (t == 0) {
        float gs = 0.f;
        for (int sl = 0; sl < 64; ++sl) gs += gate_part[sl];
        float kd = floorf(8.0f * (gs * (1.0f/262144.0f)));
        *kdyn = fminf(fmaxf(kd, 1.0f), 8.0f);
    }
}

// ---------------------------------------------------------------------------
// K4: depthwise 3x3 + FUSED group-gate resp sums. See R9 notes.
// ---------------------------------------------------------------------------
#define K4_ROWSTRIDE 264            // 4 pad | 256 data | 4 pad (floats)
#define K4_BUF (10*K4_ROWSTRIDE)    // 10 halo rows

__global__ __launch_bounds__(256,3) void k4_dw(
    const float* __restrict__ qkv, const float* __restrict__ dww,
    const float* __restrict__ pre, const float* __restrict__ cw,
    const float* __restrict__ sw,  const float* __restrict__ sb,
    float* __restrict__ v, float* __restrict__ Sg, float* __restrict__ sumsq,
    float* __restrict__ thr_sum)
{
    __shared__ float sh[2*K4_BUF];  // 21120 B

    const int t    = threadIdx.x;
    const int b    = blockIdx.x >> 8;         // 256 blocks / batch
    const int h    = (blockIdx.x >> 5) & 7;
    const int band = blockIdx.x & 31;
    const int r0   = band * 8;
    const int lr   = t >> 5;                  // output row 0..7
    const int c0   = (t & 31) * 4;            // group0 cols c0..c0+3; group1 +128
    const int lane = t & 63;

    if (t < 40) {
        int bufi = t / 20, r = (t % 20) >> 1, side = t & 1;
        sh[bufi*K4_BUF + r*K4_ROWSTRIDE + (side ? 260 : 3)] = 0.0f;
    }

    float4 reg[3];

    auto issue_loads = [&](int ch) {
        const float4* base = (const float4*)(qkv + (size_t)(b*192 + ch)*HWN);
        #pragma unroll
        for (int j = 0; j < 3; ++j) {
            int i = t + 256*j;
            float4 val = make_float4(0.f,0.f,0.f,0.f);
            if (i < 640) {
                int row = i >> 6, col4 = i & 63;
                int gy = r0 - 1 + row;
                if (gy >= 0 && gy < 256) val = base[gy*64 + col4];
            }
            reg[j] = val;
        }
    };

    auto write_lds = [&](float* buf) {
        #pragma unroll
        for (int j = 0; j < 3; ++j) {
            int i = t + 256*j;
            if (i < 640) {
                int row = i >> 6, col4 = i & 63;
                *(float4*)&buf[row*K4_ROWSTRIDE + 4 + col4*4] = reg[j];
            }
        }
    };

    auto conv8 = [&](const float* buf, const float* __restrict__ w9, float out[8]) {
        #pragma unroll
        for (int g = 0; g < 2; ++g) {
            const int cc = c0 + g*128;
            float a0=0.f, a1=0.f, a2=0.f, a3=0.f;
            #pragma unroll
            for (int rr = 0; rr < 3; ++rr) {
                const float* row = &buf[(lr+rr)*K4_ROWSTRIDE + 4 + cc];
                float4 m = *(const float4*)row;
                float l = row[-1], r = row[4];
                float w0 = w9[rr*3+0], w1 = w9[rr*3+1], w2 = w9[rr*3+2];
                a0 = fmaf(w0,l,   fmaf(w1,m.x, fmaf(w2,m.y, a0)));
                a1 = fmaf(w0,m.x, fmaf(w1,m.y, fmaf(w2,m.z, a1)));
                a2 = fmaf(w0,m.y, fmaf(w1,m.z, fmaf(w2,m.w, a2)));
                a3 = fmaf(w0,m.z, fmaf(w1,m.w, fmaf(w2,r,   a3)));
            }
            out[g*4+0]=a0; out[g*4+1]=a1; out[g*4+2]=a2; out[g*4+3]=a3;
        }
    };

    auto wsum = [&](float val) {
        val += __shfl_xor(val,1);  val += __shfl_xor(val,2);  val += __shfl_xor(val,4);
        val += __shfl_xor(val,8);  val += __shfl_xor(val,16); val += __shfl_xor(val,32);
        return val;
    };

    float dq[8][8];

    float* sq_q = &sumsq[b*128 + h*8];
    float* sq_k = &sumsq[b*128 + 64 + h*8];
    float* Sgb  = &Sg[(size_t)(b*8+h)*64];

    issue_loads(h*8 + 0);   // first q channel

    // ---- Q channels
    #pragma unroll
    for (int ch = 0; ch < 8; ++ch) {
        float* buf = sh + (ch & 1)*K4_BUF;
        write_lds(buf);
        issue_loads(ch < 7 ? (h*8 + ch + 1) : (64 + h*8));
        __syncthreads();
        conv8(buf, dww + (h*8 + ch)*9, dq[ch]);
        float ss = 0.f;
        #pragma unroll
        for (int p = 0; p < 8; ++p) ss = fmaf(dq[ch][p], dq[ch][p], ss);
        ss = wsum(ss);
        if (lane == 0) atomicAdd(&sq_q[ch], ss);
    }

    // ---- K channels
    #pragma unroll
    for (int ch = 0; ch < 8; ++ch) {
        float* buf = sh + (ch & 1)*K4_BUF;
        write_lds(buf);
        issue_loads(ch < 7 ? (64 + h*8 + ch + 1) : (128 + h*8));
        __syncthreads();
        float dk[8];
        conv8(buf, dww + (64 + h*8 + ch)*9, dk);
        float ss = 0.f;
        #pragma unroll
        for (int p = 0; p < 8; ++p) ss = fmaf(dk[p], dk[p], ss);
        ss = wsum(ss);
        if (lane == 0) atomicAdd(&sq_k[ch], ss);
        #pragma unroll
        for (int c = 0; c < 8; ++c) {
            float acc = 0.f;
            #pragma unroll
            for (int p = 0; p < 8; ++p) acc = fmaf(dq[c][p], dk[p], acc);
            acc = wsum(acc);
            if (lane == 0) atomicAdd(&Sgb[c*8 + ch], acc);
        }
    }

    // ---- V channels
    #pragma unroll
    for (int ch = 0; ch < 8; ++ch) {
        float* buf = sh + (ch & 1)*K4_BUF;
        write_lds(buf);
        if (ch < 7) issue_loads(128 + h*8 + ch + 1);
        __syncthreads();
        float dv[8];
        conv8(buf, dww + (128 + h*8 + ch)*9, dv);
        float* vb = v + (size_t)(b*64 + h*8 + ch)*HWN + (r0 + lr)*256;
        *(float4*)&vb[c0]       = make_float4(dv[0],dv[1],dv[2],dv[3]);
        *(float4*)&vb[c0 + 128] = make_float4(dv[4],dv[5],dv[6],dv[7]);
    }

    // ---- fused k3: resp partial sums for thr (this block's group g == h)
    {
        float cwr[8], swr[8];
        #pragma unroll
        for (int c = 0; c < 8; ++c) {
            cwr[c] = cw[b*64 + h*8 + c];
            swr[c] = sw[h*8 + c];
        }
        const float sbg = sb[h];
        float rs = 0.f;
        const float* preb = pre + (size_t)(b*64 + h*8)*HWN + (size_t)(r0 + lr)*256;
        #pragma unroll
        for (int g2 = 0; g2 < 2; ++g2) {
            const int cc = c0 + g2*128;
            float xc[8][4];
            float spa0 = sbg, spa1 = sbg, spa2 = sbg, spa3 = sbg;
            #pragma unroll
            for (int c = 0; c < 8; ++c) {
                float4 xv = *(const float4*)&preb[(size_t)c*HWN + cc];
                xc[c][0] = xv.x*cwr[c]; xc[c][1] = xv.y*cwr[c];
                xc[c][2] = xv.z*cwr[c]; xc[c][3] = xv.w*cwr[c];
                spa0 = fmaf(xc[c][0], swr[c], spa0);
                spa1 = fmaf(xc[c][1], swr[c], spa1);
                spa2 = fmaf(xc[c][2], swr[c], spa2);
                spa3 = fmaf(xc[c][3], swr[c], spa3);
            }
            float sp0 = sgm(spa0), sp1 = sgm(spa1), sp2 = sgm(spa2), sp3 = sgm(spa3);
            #pragma unroll
            for (int c = 0; c < 8; ++c) {
                rs += sgm(xc[c][0]*sp0);
                rs += sgm(xc[c][1]*sp1);
                rs += sgm(xc[c][2]*sp2);
                rs += sgm(xc[c][3]*sp3);
            }
        }
        rs = wsum(rs);
        if (lane == 0) atomicAdd(&thr_sum[b*8 + h], rs);
    }
}

// ---------------------------------------------------------------------------
// K6: finalize attention weights and thr. single block.
// ---------------------------------------------------------------------------
__global__ void k6_attn(const float* __restrict__ Sg, const float* __restrict__ sumsq,
                        const float* __restrict__ temp, const float* __restrict__ kdynp,
                        const float* __restrict__ thr_sum, const float* __restrict__ scales,
                        float* __restrict__ A, float* __restrict__ thr)
{
    const int t = threadIdx.x;
    if (t < 32) thr[t] = thr_sum[t] * (1.0f/(8.0f*65536.0f));
    const int b = t >> 6, h = (t >> 3) & 7, c = t & 7;
    const float kd = *kdynp;
    const float ssum = scales[0]+scales[1]+scales[2]+scales[3];
    const float nq = fmaxf(sqrtf(sumsq[b*128 + h*8 + c]), 1e-12f);
    const float tv = temp[h];
    const float* Srow = Sg + (size_t)(b*8+h)*64 + c*8;
    float a[8];
    #pragma unroll
    for (int d = 0; d < 8; ++d) {
        float nk = fmaxf(sqrtf(sumsq[b*128 + 64 + h*8 + d]), 1e-12f);
        a[d] = Srow[d] / (nq*nk) * tv;
    }
    bool keep[8];
    #pragma unroll
    for (int d = 0; d < 8; ++d) {
        int r = 0;
        #pragma unroll
        for (int e = 0; e < 8; ++e)
            r += (a[e] > a[d]) || (a[e] == a[d] && e < d);
        keep[d] = ((float)r < kd);
    }
    float m = -INFINITY;
    #pragma unroll
    for (int d = 0; d < 8; ++d) if (keep[d]) m = fmaxf(m, a[d]);
    float ex[8]; float sum = 0.f;
    #pragma unroll
    for (int d = 0; d < 8; ++d) { ex[d] = keep[d] ? expf(a[d]-m) : 0.f; sum += ex[d]; }
    const float inv = ssum / sum;
    #pragma unroll
    for (int d = 0; d < 8; ++d)
        A[(size_t)(b*8+h)*64 + c*8 + d] = ex[d]*inv;
}

// ---------------------------------------------------------------------------
// K7: mask + MFMA post conv + residual + attn@v (direct-global v) + MFMA
// out-conv with K-split operand staging.
//
// R13: LDS halved 64 -> 32 KB to double occupancy (was 2 blocks/CU, ~240 us
// latency-bound with a ~53 us memory floor):
//  (a) vt staging dropped -- attn@v reads v rows directly from global
//      (coalesced float4; hh = og>>1 is constant per thread, so each row
//      pair is loaded once and reused over j: 16 loads, no redundancy,
//      identical FP order).
//  (b) out-conv operand K-SPLIT: one 32 KB hi/lo buffer holds 64 input
//      channels at a time. Accumulate post half (ch64-127) first, barrier,
//      overwrite with attn half (ch0-63), accumulate. acc[2][8] f32x4
//      persists in registers.
// XP and each XT-half share identical [128px][32u32] geometry + swizzle.
// Peak LDS 32 KB -> 4 blocks/CU if VGPR <= 128.
// ---------------------------------------------------------------------------
__global__ __launch_bounds__(256,2) void k7_final(
    const float* __restrict__ pre, const float* __restrict__ lb, const float* __restrict__ v,
    const float* __restrict__ cw,  const float* __restrict__ thr,
    const float* __restrict__ sw,  const float* __restrict__ sb,
    const float* __restrict__ A,
    const float* __restrict__ Wpost, const float* __restrict__ bpost,
    const float* __restrict__ Wout,  float* __restrict__ out)
{
    __shared__ float smem[8192];           // 32 KB
    float* pr = smem;                      // [64 ch][128 px] fp32 (pre)
    float4* pr4 = (float4*)pr;
    // split-bf16 buffer, [128px][32 u32] hi + lo (aliases pr):
    unsigned* Bhi32 = (unsigned*)smem;
    unsigned* Blo32 = (unsigned*)(smem + 4096);
    const unsigned short* Bhi16 = (const unsigned short*)smem;
    const unsigned short* Blo16 = (const unsigned short*)(smem + 4096);

    const int t   = threadIdx.x;
    const int blk = blockIdx.x;
    const int b   = blk >> 9;            // 512 blocks per batch
    const int p0  = (blk & 511) << 7;    // 128 px / block
    const int pg  = t & 15;              // px pg*4..+3 and 64+pg*4..+3
    const int og  = t >> 4;
    const int lane = t & 63, wv = t >> 6;
    const int lm = lane & 15, lq = lane >> 4;

    // ---- stage pre only (8 float4/thread)
    const float4* pre4g = (const float4*)pre;
    #pragma unroll
    for (int i = 0; i < 8; ++i) {
        int idx = t + 256*i;
        int c = idx >> 5, q = idx & 31;
        pr4[c*32+q] = pre4g[(size_t)(b*64 + c)*16384 + (p0>>2) + q];
    }
    __syncthreads();

    // ---- mask path: read pr, masked values into registers
    float mk[4][8];
    #pragma unroll
    for (int s = 0; s < 4; ++s) {
        int task = t + 256*s;
        int g = task >> 7, px = task & 127;
        float xc[8], xv[8];
        float spa = sb[g];
        #pragma unroll
        for (int c = 0; c < 8; ++c) {
            xv[c] = pr[(g*8+c)*128 + px];
            xc[c] = xv[c]*cw[b*64 + g*8 + c];
            spa += xc[c]*sw[g*8 + c];
        }
        float sp = sgm(spa);
        float th = thr[b*8 + g];
        #pragma unroll
        for (int c = 0; c < 8; ++c) {
            float resp = sgm(xc[c]*sp);
            float mask = resp > th ? 1.0f : resp;
            mk[s][c] = xv[c]*mask;
        }
    }
    __syncthreads();   // all pr reads done

    // ---- write masked x as split-bf16 XP (overwrites pr region)
    #pragma unroll
    for (int s = 0; s < 4; ++s) {
        int task = t + 256*s;
        int g = task >> 7, px = task & 127;
        const int sw2 = (px & 7) << 2;
        const int rowb = px*32;
        #pragma unroll
        for (int c = 0; c < 8; c += 2) {
            float e0 = mk[s][c], e1 = mk[s][c+1];
            int i32 = (rowb + g*4 + (c>>1)) ^ sw2;
            Bhi32[i32] = pack_hi2(e0, e1);
            float h0 = __uint_as_float(__float_as_uint(e0)&0xFFFF0000u);
            float h1 = __uint_as_float(__float_as_uint(e1)&0xFFFF0000u);
            Blo32[i32] = pack_hi2(e0-h0, e1-h1);
        }
    }
    __syncthreads();

    // ---- post conv (64x64) via MFMA + bias + lb -> postv[8][4]
    //      and attn@v from GLOBAL v -> attv[4][8]
    float postv[8][4];
    {
        const int ot = wv;                  // 4 waves x 1 out-tile
        const int orow = ot*16 + lm;        // 0..63
        f32x4 acc[8];
        #pragma unroll
        for (int pt = 0; pt < 8; ++pt) { acc[pt][0]=0.f; acc[pt][1]=0.f; acc[pt][2]=0.f; acc[pt][3]=0.f; }
        #pragma unroll
        for (int kk = 0; kk < 2; ++kk) {
            const int cbase = kk*32 + lq*8;
            const float* wp = Wpost + orow*64 + cbase;
            float4 w0 = *(const float4*)wp;
            float4 w1 = *(const float4*)(wp+4);
            float we[8] = {w0.x,w0.y,w0.z,w0.w,w1.x,w1.y,w1.z,w1.w};
            bf16x8 Ahi, Alo;
            #pragma unroll
            for (int d = 0; d < 4; ++d) {
                float e0 = we[2*d], e1 = we[2*d+1];
                ((unsigned*)&Ahi)[d] = pack_hi2(e0, e1);
                float h0 = __uint_as_float(__float_as_uint(e0)&0xFFFF0000u);
                float h1 = __uint_as_float(__float_as_uint(e1)&0xFFFF0000u);
                ((unsigned*)&Alo)[d] = pack_hi2(e0-h0, e1-h1);
            }
            #pragma unroll
            for (int pt = 0; pt < 8; ++pt) {
                const int px = pt*16 + lm;
                const int idx = (px*64 + cbase) ^ ((px&7)<<3);
                bf16x8 Bh = *(const bf16x8*)&Bhi16[idx];
                bf16x8 Bl = *(const bf16x8*)&Blo16[idx];
                acc[pt] = __builtin_amdgcn_mfma_f32_16x16x32_bf16(Ahi, Bh, acc[pt], 0,0,0);
                acc[pt] = __builtin_amdgcn_mfma_f32_16x16x32_bf16(Ahi, Bl, acc[pt], 0,0,0);
                acc[pt] = __builtin_amdgcn_mfma_f32_16x16x32_bf16(Alo, Bh, acc[pt], 0,0,0);
            }
        }
        #pragma unroll
        for (int pt = 0; pt < 8; ++pt) {
            const int px = p0 + pt*16 + lm;
            #pragma unroll
            for (int r = 0; r < 4; ++r) {
                const int ch = ot*16 + lq*4 + r;
                postv[pt][r] = acc[pt][r] + bpost[ch]
                             + lb[(size_t)(b*64 + ch)*HWN + px];
            }
        }
    }

    float attv[4][8];
    {
        const int hh = og >> 1;
        const int cb = (og & 1) * 4;        // channel-in-head base: c = cb + j
        const float* Ab = A + (size_t)(b*8+hh)*64;
        #pragma unroll
        for (int j = 0; j < 4; ++j)
            #pragma unroll
            for (int k = 0; k < 8; ++k) attv[j][k] = 0.f;
        const float* vb = v + (size_t)(b*64 + hh*8)*HWN + p0;
        #pragma unroll
        for (int d = 0; d < 8; ++d) {
            float4 v0 = *(const float4*)&vb[(size_t)d*HWN + pg*4];
            float4 v1 = *(const float4*)&vb[(size_t)d*HWN + 64 + pg*4];
            #pragma unroll
            for (int j = 0; j < 4; ++j) {
                float av = Ab[(cb+j)*8 + d];
                attv[j][0] += av*v0.x; attv[j][1] += av*v0.y;
                attv[j][2] += av*v0.z; attv[j][3] += av*v0.w;
                attv[j][4] += av*v1.x; attv[j][5] += av*v1.y;
                attv[j][6] += av*v1.z; attv[j][7] += av*v1.w;
            }
        }
    }
    __syncthreads();   // XP reads complete -> buffer reusable

    // ---- write XT half B: POST results (input ch 64..127 of out conv)
    {
        const int ot = wv;
        const int colb = (ot*16 + lq*4) >> 1;   // u32 col 0..31
        #pragma unroll
        for (int pt = 0; pt < 8; ++pt) {
            const int px = pt*16 + lm;
            const int sw2 = (px & 7) << 2;
            const int rowb = px*32;
            float q0 = postv[pt][0], q1 = postv[pt][1];
            int i32 = (rowb + colb) ^ sw2;
            Bhi32[i32] = pack_hi2(q0, q1);
            float h0 = __uint_as_float(__float_as_uint(q0)&0xFFFF0000u);
            float h1 = __uint_as_float(__float_as_uint(q1)&0xFFFF0000u);
            Blo32[i32] = pack_hi2(q0-h0, q1-h1);
            float q2 = postv[pt][2], q3 = postv[pt][3];
            i32 = (rowb + colb + 1) ^ sw2;
            Bhi32[i32] = pack_hi2(q2, q3);
            float h2 = __uint_as_float(__float_as_uint(q2)&0xFFFF0000u);
            float h3 = __uint_as_float(__float_as_uint(q3)&0xFFFF0000u);
            Blo32[i32] = pack_hi2(q2-h2, q3-h3);
        }
    }
    __syncthreads();

    // ---- out conv accumulate: input half B (weights cols 64..127)
    f32x4 acc[2][8];
    #pragma unroll
    for (int oo = 0; oo < 2; ++oo)
        #pragma unroll
        for (int pt = 0; pt < 8; ++pt) { acc[oo][pt][0]=0.f; acc[oo][pt][1]=0.f; acc[oo][pt][2]=0.f; acc[oo][pt][3]=0.f; }
    #pragma unroll
    for (int oo = 0; oo < 2; ++oo) {
        const int ot = wv*2 + oo;
        const int orow = ot*16 + lm;
        #pragma unroll
        for (int kk = 0; kk < 2; ++kk) {
            const int cl = kk*32 + lq*8;             // local col 0..56
            const float* wp = Wout + orow*128 + 64 + cl;
            float4 w0 = *(const float4*)wp;
            float4 w1 = *(const float4*)(wp+4);
            float we[8] = {w0.x,w0.y,w0.z,w0.w,w1.x,w1.y,w1.z,w1.w};
            bf16x8 Ahi, Alo;
            #pragma unroll
            for (int d = 0; d < 4; ++d) {
                float e0 = we[2*d], e1 = we[2*d+1];
                ((unsigned*)&Ahi)[d] = pack_hi2(e0, e1);
                float h0 = __uint_as_float(__float_as_uint(e0)&0xFFFF0000u);
                float h1 = __uint_as_float(__float_as_uint(e1)&0xFFFF0000u);
                ((unsigned*)&Alo)[d] = pack_hi2(e0-h0, e1-h1);
            }
            #pragma unroll
            for (int pt = 0; pt < 8; ++pt) {
                const int px = pt*16 + lm;
                const int idx = (px*64 + cl) ^ ((px&7)<<3);
                bf16x8 Bh = *(const bf16x8*)&Bhi16[idx];
                bf16x8 Bl = *(const bf16x8*)&Blo16[idx];
                acc[oo][pt] = __builtin_amdgcn_mfma_f32_16x16x32_bf16(Ahi, Bh, acc[oo][pt], 0,0,0);
                acc[oo][pt] = __builtin_amdgcn_mfma_f32_16x16x32_bf16(Ahi, Bl, acc[oo][pt], 0,0,0);
                acc[oo][pt] = __builtin_amdgcn_mfma_f32_16x16x32_bf16(Alo, Bh, acc[oo][pt], 0,0,0);
            }
        }
    }
    __syncthreads();   // half-B reads done

    // ---- write XT half A: ATTN results (input ch 0..63 of out conv)
    {
        #pragma unroll
        for (int half = 0; half < 2; ++half) {
            #pragma unroll
            for (int k = 0; k < 4; ++k) {
                const int px = half*64 + pg*4 + k;
                const int sw2 = (px & 7) << 2;
                const int rowb = px*32;
                #pragma unroll
                for (int jj = 0; jj < 4; jj += 2) {
                    float a0 = attv[jj][half*4+k], a1 = attv[jj+1][half*4+k];
                    int i32 = (rowb + ((og*4+jj)>>1)) ^ sw2;
                    Bhi32[i32] = pack_hi2(a0, a1);
                    float ah0 = __uint_as_float(__float_as_uint(a0)&0xFFFF0000u);
                    float ah1 = __uint_as_float(__float_as_uint(a1)&0xFFFF0000u);
                    Blo32[i32] = pack_hi2(a0-ah0, a1-ah1);
                }
            }
        }
    }
    __syncthreads();

    // ---- out conv accumulate: input half A (weights cols 0..63), then store
    #pragma unroll
    for (int oo = 0; oo < 2; ++oo) {
        const int ot = wv*2 + oo;
        const int orow = ot*16 + lm;
        #pragma unroll
        for (int kk = 0; kk < 2; ++kk) {
            const int cl = kk*32 + lq*8;
            const float* wp = Wout + orow*128 + cl;
            float4 w0 = *(const float4*)wp;
            float4 w1 = *(const float4*)(wp+4);
            float we[8] = {w0.x,w0.y,w0.z,w0.w,w1.x,w1.y,w1.z,w1.w};
            bf16x8 Ahi, Alo;
            #pragma unroll
            for (int d = 0; d < 4; ++d) {
                float e0 = we[2*d], e1 = we[2*d+1];
                ((unsigned*)&Ahi)[d] = pack_hi2(e0, e1);
                float h0 = __uint_as_float(__float_as_uint(e0)&0xFFFF0000u);
                float h1 = __uint_as_float(__float_as_uint(e1)&0xFFFF0000u);
                ((unsigned*)&Alo)[d] = pack_hi2(e0-h0, e1-h1);
            }
            #pragma unroll
            for (int pt = 0; pt < 8; ++pt) {
                const int px = pt*16 + lm;
                const int idx = (px*64 + cl) ^ ((px&7)<<3);
                bf16x8 Bh = *(const bf16x8*)&Bhi16[idx];
                bf16x8 Bl = *(const bf16x8*)&Blo16[idx];
                acc[oo][pt] = __builtin_amdgcn_mfma_f32_16x16x32_bf16(Ahi, Bh, acc[oo][pt], 0,0,0);
                acc[oo][pt] = __builtin_amdgcn_mfma_f32_16x16x32_bf16(Ahi, Bl, acc[oo][pt], 0,0,0);
                acc[oo][pt] = __builtin_amdgcn_mfma_f32_16x16x32_bf16(Alo, Bh, acc[oo][pt], 0,0,0);
            }
        }
        #pragma unroll
        for (int pt = 0; pt < 8; ++pt) {
            const int px = p0 + pt*16 + lm;
            #pragma unroll
            for (int r = 0; r < 4; ++r) {
                const int ch = ot*16 + lq*4 + r;
                out[(size_t)(b*128 + ch)*HWN + px] = acc[oo][pt][r];
            }
        }
    }
}

// ---------------------------------------------------------------------------
extern "C" void kernel_launch(void* const* d_in, const int* in_sizes, int n_in,
                              void* d_out, int out_size, void* d_ws, size_t ws_size,
                              hipStream_t stream)
{
    const float* x     = (const float*)d_in[0];
    const float* Wp    = (const float*)d_in[1];
    const float* Wpre  = (const float*)d_in[2];
    const float* bpre  = (const float*)d_in[3];
    const float* w1    = (const float*)d_in[4];
    const float* b1    = (const float*)d_in[5];
    const float* w2    = (const float*)d_in[6];
    const float* b2    = (const float*)d_in[7];
    const float* sw    = (const float*)d_in[8];
    const float* sb    = (const float*)d_in[9];
    const float* Wpost = (const float*)d_in[10];
    const float* bpost = (const float*)d_in[11];
    const float* Wqkv  = (const float*)d_in[12];
    const float* dww   = (const float*)d_in[13];
    const float* Wg1   = (const float*)d_in[14];
    const float* bg1   = (const float*)d_in[15];
    const float* wg2   = (const float*)d_in[16];
    const float* bg2   = (const float*)d_in[17];
    const float* temp  = (const float*)d_in[18];
    const float* scales= (const float*)d_in[19];
    const float* Wout  = (const float*)d_in[20];
    float* out = (float*)d_out;

    float* ws = (float*)d_ws;
    float* pooled_part = ws;                 // 16384
    float* gate_part   = ws + 16384;         // 64
    float* thr_sum     = ws + 16448;         // 32
    float* sumsq       = ws + 16480;         // 512
    float* Sg          = ws + 16992;         // 2048
    float* cw          = ws + 19040;         // 256
    float* kdyn        = ws + 19296;         // 1
    float* thr         = ws + 19328;         // 32
    float* A           = ws + 19360;         // 2048

    float* lb  = ws + 32768;
    float* pre = lb  + 16777216;
    float* qkv = pre + 16777216;
    float* v   = qkv + 50331648;

    hipMemsetAsync(ws, 0, (size_t)19040*sizeof(float), stream);

    k1_proj <<<2048, 256, 0, stream>>>(x, Wp, Wpre, bpre, Wqkv, Wg1, bg1, wg2, bg2,
                                       lb, pre, qkv, pooled_part, gate_part);
    k2_small<<<1,    256, 0, stream>>>(pooled_part, gate_part, w1, b1, w2, b2, cw, kdyn);
    k4_dw   <<<1024, 256, 0, stream>>>(qkv, dww, pre, cw, sw, sb, v, Sg, sumsq, thr_sum);
    k6_attn <<<1,    256, 0, stream>>>(Sg, sumsq, temp, kdyn, thr_sum, scales, A, thr);
    k7_final<<<2048, 256, 0, stream>>>(pre, lb, v, cw, thr, sw, sb, A,
                                       Wpost, bpost, Wout, out);
}